// Round 2
// baseline (143.502 us; speedup 1.0000x reference)
//
#include <hip/hip_runtime.h>
#include <math.h>

// Cosine similarity per matching row: out[r] = dot(a[r,:], b[r,:]) /
// (||a[r,:]|| * ||b[r,:]||), D = 256 floats per row, eps-guarded.
//
// Round-2 design: 8 lanes per row (8 lanes x 8 float4 = 256 floats).
// Each wave handles 8 rows per iteration with 16 independent float4 loads
// per lane in flight (deep MLP), then a 3-step butterfly reduce within each
// 8-lane group (9 shuffles per 8 rows vs 18 per row in round 1).
// Grid-stride loop amortizes block launch; 1024 blocks = 4 blocks/CU.

#define EPS 1e-12f

__global__ __launch_bounds__(256) void cosine_rows_kernel(
    const float4* __restrict__ a4,
    const float4* __restrict__ b4,
    float* __restrict__ out,
    int nrows)
{
    const int lane = threadIdx.x & 63;
    const int sl   = lane & 7;    // lane within the 8-lane row group
    const int sub  = lane >> 3;   // which of the wave's 8 rows
    const int waveGlobal = (blockIdx.x << 2) + (threadIdx.x >> 6);
    const int totalWaves = gridDim.x << 2;

    for (int rowbase = waveGlobal * 8; rowbase < nrows; rowbase += totalWaves * 8) {
        const int row = rowbase + sub;
        if (row >= nrows) break;

        // Row = 64 float4s; lane sl takes float4s sl, sl+8, ..., sl+56.
        const float4* __restrict__ ap = a4 + row * 64 + sl;
        const float4* __restrict__ bp = b4 + row * 64 + sl;

        float4 av[8], bv[8];
        #pragma unroll
        for (int j = 0; j < 8; ++j) av[j] = ap[j * 8];
        #pragma unroll
        for (int j = 0; j < 8; ++j) bv[j] = bp[j * 8];

        float saa = 0.f, sbb = 0.f, sab = 0.f;
        #pragma unroll
        for (int j = 0; j < 8; ++j) {
            saa = fmaf(av[j].x, av[j].x, saa);
            saa = fmaf(av[j].y, av[j].y, saa);
            saa = fmaf(av[j].z, av[j].z, saa);
            saa = fmaf(av[j].w, av[j].w, saa);
            sbb = fmaf(bv[j].x, bv[j].x, sbb);
            sbb = fmaf(bv[j].y, bv[j].y, sbb);
            sbb = fmaf(bv[j].z, bv[j].z, sbb);
            sbb = fmaf(bv[j].w, bv[j].w, sbb);
            sab = fmaf(av[j].x, bv[j].x, sab);
            sab = fmaf(av[j].y, bv[j].y, sab);
            sab = fmaf(av[j].z, bv[j].z, sab);
            sab = fmaf(av[j].w, bv[j].w, sab);
        }

        // Butterfly reduce within each 8-lane group (xor 1,2,4 stays in-group).
        #pragma unroll
        for (int off = 1; off < 8; off <<= 1) {
            saa += __shfl_xor(saa, off, 64);
            sbb += __shfl_xor(sbb, off, 64);
            sab += __shfl_xor(sab, off, 64);
        }

        if (sl == 0) {
            const float denom = sqrtf(fmaxf(saa, EPS)) * sqrtf(fmaxf(sbb, EPS));
            out[row] = sab / denom;
        }
    }
}

extern "C" void kernel_launch(void* const* d_in, const int* in_sizes, int n_in,
                              void* d_out, int out_size, void* d_ws, size_t ws_size,
                              hipStream_t stream) {
    const float* a = (const float*)d_in[0];
    const float* b = (const float*)d_in[1];
    float* out = (float*)d_out;

    const int nrows = out_size;   // 16 * 4096 = 65536
    const int blocks = 1024;      // 4 blocks/CU; each wave: 2 groups of 8 rows

    cosine_rows_kernel<<<blocks, 256, 0, stream>>>(
        (const float4*)a, (const float4*)b, out, nrows);
}

// Round 4
// 136.754 us; speedup vs baseline: 1.0493x; 1.0493x over previous
//
#include <hip/hip_runtime.h>
#include <math.h>

// Cosine similarity per matching row: out[r] = dot(a[r,:], b[r,:]) /
// (||a[r,:]|| * ||b[r,:]||), D = 256 floats per row, eps-guarded.
//
// Round-4 (= round-3 fixed): discriminate "read-path ceiling (~3 TB/s)" vs
// "kernel structure".
//  - 1 wave per row-quad per iteration: 8 contiguous 1 KiB wave-loads
//    (4 rows x {a,b}) issued back-to-back into NAMED registers (true 8-deep
//    MLP; round 2's compiler only had 32 VGPRs and serialized).
//  - __builtin_nontemporal_load on a native ext_vector_type(4) float --
//    HIP's float4 class is rejected by the builtin; the native vector lowers
//    to global_load_dwordx4 with the nt flag (bypasses cache allocation).
//  - 2048 blocks grid-stride = 8 blocks/CU target, full occupancy.

#define EPS 1e-12f

typedef float f4 __attribute__((ext_vector_type(4)));

__global__ __launch_bounds__(256) void cosine_rows_kernel(
    const f4* __restrict__ a4,
    const f4* __restrict__ b4,
    float* __restrict__ out,
    int nrows)
{
    const int lane = threadIdx.x & 63;
    const int wid  = (blockIdx.x << 2) + (threadIdx.x >> 6);
    const int nw   = gridDim.x << 2;

    for (int base = wid * 4; base < nrows; base += nw * 4) {
        // 8 independent 1 KiB wave-loads, all issued before any use.
        const int i0 = (base + 0) * 64 + lane;
        const int i1 = (base + 1) * 64 + lane;
        const int i2 = (base + 2) * 64 + lane;
        const int i3 = (base + 3) * 64 + lane;
        f4 av0 = __builtin_nontemporal_load(&a4[i0]);
        f4 av1 = __builtin_nontemporal_load(&a4[i1]);
        f4 av2 = __builtin_nontemporal_load(&a4[i2]);
        f4 av3 = __builtin_nontemporal_load(&a4[i3]);
        f4 bv0 = __builtin_nontemporal_load(&b4[i0]);
        f4 bv1 = __builtin_nontemporal_load(&b4[i1]);
        f4 bv2 = __builtin_nontemporal_load(&b4[i2]);
        f4 bv3 = __builtin_nontemporal_load(&b4[i3]);

        f4 avs[4] = {av0, av1, av2, av3};
        f4 bvs[4] = {bv0, bv1, bv2, bv3};

        #pragma unroll
        for (int r = 0; r < 4; ++r) {
            const f4 av = avs[r];
            const f4 bv = bvs[r];
            float saa = av.x * av.x + av.y * av.y + av.z * av.z + av.w * av.w;
            float sbb = bv.x * bv.x + bv.y * bv.y + bv.z * bv.z + bv.w * bv.w;
            float sab = av.x * bv.x + av.y * bv.y + av.z * bv.z + av.w * bv.w;

            #pragma unroll
            for (int off = 32; off > 0; off >>= 1) {
                saa += __shfl_xor(saa, off, 64);
                sbb += __shfl_xor(sbb, off, 64);
                sab += __shfl_xor(sab, off, 64);
            }

            if (lane == 0) {
                const float denom = sqrtf(fmaxf(saa, EPS)) * sqrtf(fmaxf(sbb, EPS));
                out[base + r] = sab / denom;
            }
        }
    }
}

extern "C" void kernel_launch(void* const* d_in, const int* in_sizes, int n_in,
                              void* d_out, int out_size, void* d_ws, size_t ws_size,
                              hipStream_t stream) {
    const float* a = (const float*)d_in[0];
    const float* b = (const float*)d_in[1];
    float* out = (float*)d_out;

    const int nrows = out_size;   // 16 * 4096 = 65536 (divisible by 4)
    const int blocks = 2048;      // 8 blocks/CU target; 2 sweeps per wave

    cosine_rows_kernel<<<blocks, 256, 0, stream>>>(
        (const f4*)a, (const f4*)b, out, nrows);
}